// Round 7
// baseline (92.672 us; speedup 1.0000x reference)
//
#include <hip/hip_runtime.h>
#include <hip/hip_bf16.h>

// Problem geometry
#define HSZ 256
#define WSZ 256
#define BC  16          // b*c
#define NCH 64          // 8x8 window channels
#define PADLO 3         // reflect pad (3,4)

// Tiling: full-width stripe. Block = 512 threads = 8 waves; wave = 1 output row.
#define TH 8            // rows per block
#define NTHR 512
#define TR (TH + 7)     // 15 halo rows
#define TC (WSZ + 7)    // 263 halo cols
#define TSTRIDE 264     // padded LDS row stride (floats), 16B-aligned rows

typedef short bf16x8 __attribute__((ext_vector_type(8)));
typedef float f32x4  __attribute__((ext_vector_type(4)));
typedef unsigned int u32x4 __attribute__((ext_vector_type(4)));

__device__ __forceinline__ int reflect_idx(int i) {
    i = (i < 0) ? -i : i;
    i = (i >= HSZ) ? (2 * (HSZ - 1) - i) : i;
    return i;
}

// fp32 -> bf16 RNE (build kernel only)
__device__ __forceinline__ unsigned short f2bf(float f) {
    unsigned u = __builtin_bit_cast(unsigned, f);
    u += 0x7FFFu + ((u >> 16) & 1u);
    return (unsigned short)(u >> 16);
}

// packed fp32x2 -> bf16x2 (v_cvt_pk_bf16_f32), RNE — same rounding as f2bf
__device__ __forceinline__ unsigned pk2(float a, float b) {
    __hip_bfloat162 h = __float22bfloat162_rn(make_float2(a, b));
    unsigned r;
    __builtin_memcpy(&r, &h, sizeof(r));
    return r;
}

// ---------------------------------------------------------------------------
// Kernel 1: A = prod_i (I - 2 v_i v_i^T/||v_i||^2), 256 threads.
// 4 lanes per row (lane owns 16 cols); dots reduced via shfl_xor(16,32).
// Wave w emits bf16 A-fragments for m-block mb=w:
//   frag(mb,c): lane l, elem j = A[k = c*32 + (l>>4)*8 + j][mb*16 + (l&15)]
// ws layout: ushort frags[4][2][64][8]  (8 KB)
// ---------------------------------------------------------------------------
__global__ void build_A_frags(const float* __restrict__ v,
                              unsigned short* __restrict__ frags) {
    __shared__ float As[64][64];
    const int t = threadIdx.x;
    const int w = t >> 6;
    const int l = t & 63;
    const int r = (w << 4) | (l & 15);
    const int q = l >> 4;

    float row[16];
#pragma unroll
    for (int c = 0; c < 16; ++c) row[c] = (q * 16 + c == r) ? 1.0f : 0.0f;

    for (int i = 0; i < 64; ++i) {
        const f32x4* vp = (const f32x4*)(v + i * 64 + q * 16);
        f32x4 v0 = vp[0], v1 = vp[1], v2 = vp[2], v3 = vp[3];
        float vv[16];
#pragma unroll
        for (int j = 0; j < 4; ++j) { vv[j] = v0[j]; vv[4+j] = v1[j]; vv[8+j] = v2[j]; vv[12+j] = v3[j]; }

        float s0 = 0, s1 = 0, s2 = 0, s3 = 0, a0 = 0, a1 = 0, a2 = 0, a3 = 0;
#pragma unroll
        for (int c = 0; c < 4; ++c) {
            s0 = fmaf(vv[c],     vv[c],     s0);
            s1 = fmaf(vv[4+c],   vv[4+c],   s1);
            s2 = fmaf(vv[8+c],   vv[8+c],   s2);
            s3 = fmaf(vv[12+c],  vv[12+c],  s3);
            a0 = fmaf(row[c],    vv[c],     a0);
            a1 = fmaf(row[4+c],  vv[4+c],   a1);
            a2 = fmaf(row[8+c],  vv[8+c],   a2);
            a3 = fmaf(row[12+c], vv[12+c],  a3);
        }
        float s  = (s0 + s1) + (s2 + s3);
        float av = (a0 + a1) + (a2 + a3);
        av += __shfl_xor(av, 16); s += __shfl_xor(s, 16);
        av += __shfl_xor(av, 32); s += __shfl_xor(s, 32);

        const float scale = 2.0f * av / s;
#pragma unroll
        for (int c = 0; c < 16; ++c) row[c] = fmaf(-scale, vv[c], row[c]);
    }
#pragma unroll
    for (int c = 0; c < 16; ++c) As[r][q * 16 + c] = row[c];
    __syncthreads();

    const int ln = l & 15, lh = l >> 4;
    const int mb = w;
#pragma unroll
    for (int c2 = 0; c2 < 2; ++c2)
#pragma unroll
        for (int j = 0; j < 8; ++j) {
            float val = As[c2 * 32 + lh * 8 + j][mb * 16 + ln];
            frags[(((mb * 2 + c2) * 64) + l) * 8 + j] = f2bf(val);
        }
}

// ---------------------------------------------------------------------------
// Kernel 2: full-width stripe. Wave = one output row (256 px x 64 ch), loop
// over 4 x-quarters. Per (ch,row) the full 1 KB line is written by one wave
// within one ry iteration (DRAM-friendly). Plain (cached) stores — L2
// write-back smooths the burst like the fill kernel.
// ---------------------------------------------------------------------------
__global__ __launch_bounds__(512)
void ortho_mfma_kernel(const float* __restrict__ x,
                       const unsigned short* __restrict__ frags,
                       float* __restrict__ out) {
    __shared__ float tile[TR][TSTRIDE];

    const int b  = blockIdx.y;
    const int y0 = blockIdx.x * TH;
    const float* __restrict__ xb = x + (size_t)b * (HSZ * WSZ);

    const int tx = threadIdx.x;   // lane 0..63
    const int ty = threadIdx.y;   // wave 0..7
    const int tid = ty * 64 + tx;

    // Stage halo tile (15 x 263) with reflect padding; linear, coalesced.
    for (int idx = tid; idx < TR * TC; idx += NTHR) {
        const int r = idx / TC;
        const int c = idx - r * TC;
        tile[r][c] = xb[(size_t)reflect_idx(y0 + r - PADLO) * WSZ + reflect_idx(c - PADLO)];
    }

    const int ln = tx & 15, lh = tx >> 4;

    // Hoist A fragments (8 x 16B, L2-hot)
    bf16x8 af[4][2];
#pragma unroll
    for (int mb = 0; mb < 4; ++mb)
#pragma unroll
        for (int c = 0; c < 2; ++c)
            af[mb][c] = *(const bf16x8*)(frags + ((mb * 2 + c) * 64 + tx) * 8);

    __syncthreads();

    const int y = y0 + ty;
    float* __restrict__ outrow =
        out + (size_t)b * NCH * (HSZ * WSZ) + (size_t)y * WSZ;

#pragma unroll
    for (int qq = 0; qq < 4; ++qq) {
        // Per k-chunk: 12 fp32 (elems 0..10 used) -> 6 packed bf16x2 dwords
        unsigned d[2][6];
#pragma unroll
        for (int c = 0; c < 2; ++c) {
            const f32x4* rp = (const f32x4*)&tile[ty + 4 * c + lh][64 * qq + 4 * ln];
            f32x4 q0 = rp[0], q1 = rp[1], q2 = rp[2];
            d[c][0] = pk2(q0[0], q0[1]);
            d[c][1] = pk2(q0[2], q0[3]);
            d[c][2] = pk2(q1[0], q1[1]);
            d[c][3] = pk2(q1[2], q1[3]);
            d[c][4] = pk2(q2[0], q2[1]);
            d[c][5] = pk2(q2[2], q2[3]);
        }

        // Fragments: g even -> dword window; g odd -> 16-bit merges
        bf16x8 bfr[2][4];
#pragma unroll
        for (int c = 0; c < 2; ++c) {
            const unsigned* dc = d[c];
            u32x4 w0 = { dc[0], dc[1], dc[2], dc[3] };                   // e0..7
            u32x4 w2 = { dc[1], dc[2], dc[3], dc[4] };                   // e2..9
            u32x4 w1 = { (dc[0] >> 16) | (dc[1] << 16),                 // e1..8
                         (dc[1] >> 16) | (dc[2] << 16),
                         (dc[2] >> 16) | (dc[3] << 16),
                         (dc[3] >> 16) | (dc[4] << 16) };
            u32x4 w3 = { (dc[1] >> 16) | (dc[2] << 16),                 // e3..10
                         (dc[2] >> 16) | (dc[3] << 16),
                         (dc[3] >> 16) | (dc[4] << 16),
                         (dc[4] >> 16) | (dc[5] << 16) };
            bfr[c][0] = __builtin_bit_cast(bf16x8, w0);
            bfr[c][1] = __builtin_bit_cast(bf16x8, w1);
            bfr[c][2] = __builtin_bit_cast(bf16x8, w2);
            bfr[c][3] = __builtin_bit_cast(bf16x8, w3);
        }

        float* __restrict__ outq = outrow + 64 * qq + 4 * ln;

#pragma unroll
        for (int mb = 0; mb < 4; ++mb) {
            f32x4 acc[4];
#pragma unroll
            for (int g = 0; g < 4; ++g) {
                acc[g] = (f32x4){0.0f, 0.0f, 0.0f, 0.0f};
                acc[g] = __builtin_amdgcn_mfma_f32_16x16x32_bf16(af[mb][0], bfr[0][g], acc[g], 0, 0, 0);
                acc[g] = __builtin_amdgcn_mfma_f32_16x16x32_bf16(af[mb][1], bfr[1][g], acc[g], 0, 0, 0);
            }
#pragma unroll
            for (int r = 0; r < 4; ++r) {
                const int ch = mb * 16 + lh * 4 + r;
                f32x4 vv = { acc[0][r], acc[1][r], acc[2][r], acc[3][r] };
                *(f32x4*)&outq[(size_t)ch * (HSZ * WSZ)] = vv;
            }
        }
    }
}

// ---------------------------------------------------------------------------
extern "C" void kernel_launch(void* const* d_in, const int* in_sizes, int n_in,
                              void* d_out, int out_size, void* d_ws, size_t ws_size,
                              hipStream_t stream) {
    const float* x = (const float*)d_in[0];        // [2,8,256,256] fp32
    const float* v = (const float*)d_in[1];        // [64,64] fp32
    float* outp = (float*)d_out;                   // [16,64,256,256] fp32
    unsigned short* frags = (unsigned short*)d_ws; // 4*2*64*8 bf16 = 8 KB

    build_A_frags<<<1, 256, 0, stream>>>(v, frags);

    dim3 grid(HSZ / TH, BC);                       // 32 x 16 = 512 blocks
    dim3 block(64, TH);                            // 512 threads = 8 waves
    ortho_mfma_kernel<<<grid, block, 0, stream>>>(x, frags, outp);
}

// Round 8
// 85.238 us; speedup vs baseline: 1.0872x; 1.0872x over previous
//
#include <hip/hip_runtime.h>
#include <hip/hip_bf16.h>

// Problem geometry
#define HSZ 256
#define WSZ 256
#define BC  16          // b*c
#define NCH 64          // 8x8 window channels
#define HW  (HSZ * WSZ)
#define PADLO 3         // reflect pad (3,4)

// Tiling: full-width stripe, block = 256 threads = 4 waves, TH=8 rows,
// each wave computes 2 full 256-px output rows (sequentially).
#define TH 8
#define NTHR 256
#define TR (TH + 7)     // 15 halo rows
#define TC (WSZ + 7)    // 263 halo cols
#define TSTRIDE 264     // padded LDS row stride (floats)
#define OBUFW 260       // out-transpose buffer row stride (260 dwords: +4 pad)

typedef short bf16x8 __attribute__((ext_vector_type(8)));
typedef float f32x4  __attribute__((ext_vector_type(4)));
typedef unsigned int u32x4 __attribute__((ext_vector_type(4)));

__device__ __forceinline__ int reflect_idx(int i) {
    i = (i < 0) ? -i : i;
    i = (i >= HSZ) ? (2 * (HSZ - 1) - i) : i;
    return i;
}

// fp32 -> bf16 RNE (build kernel only)
__device__ __forceinline__ unsigned short f2bf(float f) {
    unsigned u = __builtin_bit_cast(unsigned, f);
    u += 0x7FFFu + ((u >> 16) & 1u);
    return (unsigned short)(u >> 16);
}

// packed fp32x2 -> bf16x2 (v_cvt_pk_bf16_f32), RNE
__device__ __forceinline__ unsigned pk2(float a, float b) {
    __hip_bfloat162 h = __float22bfloat162_rn(make_float2(a, b));
    unsigned r;
    __builtin_memcpy(&r, &h, sizeof(r));
    return r;
}

// ---------------------------------------------------------------------------
// Kernel 1: A = prod_i (I - 2 v_i v_i^T/||v_i||^2), 256 threads (unchanged,
// validated). Wave w emits bf16 A-fragments for m-block mb=w:
//   frag(mb,c): lane l, elem j = A[k = c*32 + (l>>4)*8 + j][mb*16 + (l&15)]
// ws layout: ushort frags[4][2][64][8]  (8 KB)
// ---------------------------------------------------------------------------
__global__ void build_A_frags(const float* __restrict__ v,
                              unsigned short* __restrict__ frags) {
    __shared__ float As[64][64];
    const int t = threadIdx.x;
    const int w = t >> 6;
    const int l = t & 63;
    const int r = (w << 4) | (l & 15);
    const int q = l >> 4;

    float row[16];
#pragma unroll
    for (int c = 0; c < 16; ++c) row[c] = (q * 16 + c == r) ? 1.0f : 0.0f;

    for (int i = 0; i < 64; ++i) {
        const f32x4* vp = (const f32x4*)(v + i * 64 + q * 16);
        f32x4 v0 = vp[0], v1 = vp[1], v2 = vp[2], v3 = vp[3];
        float vv[16];
#pragma unroll
        for (int j = 0; j < 4; ++j) { vv[j] = v0[j]; vv[4+j] = v1[j]; vv[8+j] = v2[j]; vv[12+j] = v3[j]; }

        float s0 = 0, s1 = 0, s2 = 0, s3 = 0, a0 = 0, a1 = 0, a2 = 0, a3 = 0;
#pragma unroll
        for (int c = 0; c < 4; ++c) {
            s0 = fmaf(vv[c],     vv[c],     s0);
            s1 = fmaf(vv[4+c],   vv[4+c],   s1);
            s2 = fmaf(vv[8+c],   vv[8+c],   s2);
            s3 = fmaf(vv[12+c],  vv[12+c],  s3);
            a0 = fmaf(row[c],    vv[c],     a0);
            a1 = fmaf(row[4+c],  vv[4+c],   a1);
            a2 = fmaf(row[8+c],  vv[8+c],   a2);
            a3 = fmaf(row[12+c], vv[12+c],  a3);
        }
        float s  = (s0 + s1) + (s2 + s3);
        float av = (a0 + a1) + (a2 + a3);
        av += __shfl_xor(av, 16); s += __shfl_xor(s, 16);
        av += __shfl_xor(av, 32); s += __shfl_xor(s, 32);

        const float scale = 2.0f * av / s;
#pragma unroll
        for (int c = 0; c < 16; ++c) row[c] = fmaf(-scale, vv[c], row[c]);
    }
#pragma unroll
    for (int c = 0; c < 16; ++c) As[r][q * 16 + c] = row[c];
    __syncthreads();

    const int ln = l & 15, lh = l >> 4;
    const int mb = w;
#pragma unroll
    for (int c2 = 0; c2 < 2; ++c2)
#pragma unroll
        for (int j = 0; j < 8; ++j) {
            float val = As[c2 * 32 + lh * 8 + j][mb * 16 + ln];
            frags[(((mb * 2 + c2) * 64) + l) * 8 + j] = f2bf(val);
        }
}

// ---------------------------------------------------------------------------
// Kernel 2: wave = one full 256-px output row (x2). Per mb (16 channels):
// accumulate all 4 x-quarters (acc[qq][g]), then per r transpose via per-wave
// LDS buffer so each global store writes ONE complete (ch,row) 1 KB line
// (64 lanes x 16 B contiguous, nontemporal) — DRAM-page-friendly runs.
// ---------------------------------------------------------------------------
__global__ __launch_bounds__(256)
void ortho_mfma_kernel(const float* __restrict__ x,
                       const unsigned short* __restrict__ frags,
                       float* __restrict__ out) {
    __shared__ float tile[TR][TSTRIDE];          // 15.8 KB
    __shared__ float obuf[4][4][OBUFW];          // 16.6 KB, per-wave [4ch][260]

    const int b  = blockIdx.y;
    const int y0 = blockIdx.x * TH;
    const float* __restrict__ xb = x + (size_t)b * HW;

    const int tx = threadIdx.x;   // lane 0..63
    const int wv = threadIdx.y;   // wave 0..3
    const int tid = wv * 64 + tx;

    // Stage halo tile (15 x 263) with reflect padding; linear, coalesced.
    for (int idx = tid; idx < TR * TC; idx += NTHR) {
        const int r = idx / TC;
        const int c = idx - r * TC;
        tile[r][c] = xb[(size_t)reflect_idx(y0 + r - PADLO) * WSZ + reflect_idx(c - PADLO)];
    }
    __syncthreads();

    const int ln = tx & 15, lh = tx >> 4;

#pragma unroll
    for (int rr = 0; rr < 2; ++rr) {
        const int tyr = wv * 2 + rr;            // tile-relative output row
        const int y   = y0 + tyr;

        // Convert the full row's B-data once: 4 qq x 2 chunks x 12 fp32 -> 6 dwords
        unsigned d[4][2][6];
#pragma unroll
        for (int qq = 0; qq < 4; ++qq)
#pragma unroll
            for (int c = 0; c < 2; ++c) {
                const f32x4* rp = (const f32x4*)&tile[tyr + 4 * c + lh][64 * qq + 4 * ln];
                f32x4 q0 = rp[0], q1 = rp[1], q2 = rp[2];
                d[qq][c][0] = pk2(q0[0], q0[1]);
                d[qq][c][1] = pk2(q0[2], q0[3]);
                d[qq][c][2] = pk2(q1[0], q1[1]);
                d[qq][c][3] = pk2(q1[2], q1[3]);
                d[qq][c][4] = pk2(q2[0], q2[1]);
                d[qq][c][5] = pk2(q2[2], q2[3]);
            }

        float* __restrict__ outrow = out + (size_t)b * NCH * HW + (size_t)y * WSZ;

#pragma unroll
        for (int mb = 0; mb < 4; ++mb) {
            const bf16x8 af0 = *(const bf16x8*)(frags + ((mb * 2 + 0) * 64 + tx) * 8);
            const bf16x8 af1 = *(const bf16x8*)(frags + ((mb * 2 + 1) * 64 + tx) * 8);

            f32x4 acc[4][4];   // [qq][g]
#pragma unroll
            for (int qq = 0; qq < 4; ++qq) {
                // Rebuild fragments for this qq from cached dwords (alignbit merges)
                bf16x8 bfr[2][4];
#pragma unroll
                for (int c = 0; c < 2; ++c) {
                    const unsigned* dc = d[qq][c];
                    u32x4 w0 = { dc[0], dc[1], dc[2], dc[3] };                  // e0..7
                    u32x4 w2 = { dc[1], dc[2], dc[3], dc[4] };                  // e2..9
                    u32x4 w1 = { (dc[0] >> 16) | (dc[1] << 16),                // e1..8
                                 (dc[1] >> 16) | (dc[2] << 16),
                                 (dc[2] >> 16) | (dc[3] << 16),
                                 (dc[3] >> 16) | (dc[4] << 16) };
                    u32x4 w3 = { (dc[1] >> 16) | (dc[2] << 16),                // e3..10
                                 (dc[2] >> 16) | (dc[3] << 16),
                                 (dc[3] >> 16) | (dc[4] << 16),
                                 (dc[4] >> 16) | (dc[5] << 16) };
                    bfr[c][0] = __builtin_bit_cast(bf16x8, w0);
                    bfr[c][1] = __builtin_bit_cast(bf16x8, w1);
                    bfr[c][2] = __builtin_bit_cast(bf16x8, w2);
                    bfr[c][3] = __builtin_bit_cast(bf16x8, w3);
                }
#pragma unroll
                for (int g = 0; g < 4; ++g) {
                    acc[qq][g] = (f32x4){0.0f, 0.0f, 0.0f, 0.0f};
                    acc[qq][g] = __builtin_amdgcn_mfma_f32_16x16x32_bf16(af0, bfr[0][g], acc[qq][g], 0, 0, 0);
                    acc[qq][g] = __builtin_amdgcn_mfma_f32_16x16x32_bf16(af1, bfr[1][g], acc[qq][g], 0, 0, 0);
                }
            }

            // Store phase: per r, wave-local LDS transpose -> four 1 KB line stores
#pragma unroll
            for (int r = 0; r < 4; ++r) {
#pragma unroll
                for (int qq = 0; qq < 4; ++qq) {
                    f32x4 wvec = { acc[qq][0][r], acc[qq][1][r], acc[qq][2][r], acc[qq][3][r] };
                    *(f32x4*)&obuf[wv][lh][64 * qq + 4 * ln] = wvec;   // px 64qq+4ln+g
                }
                // compiler inserts lgkmcnt wait (obuf write->read dependence)
#pragma unroll
                for (int j = 0; j < 4; ++j) {
                    f32x4 ov = *(const f32x4*)&obuf[wv][j][4 * tx];
                    const int ch = mb * 16 + j * 4 + r;
                    __builtin_nontemporal_store(ov, (f32x4*)&outrow[(size_t)ch * HW + 4 * tx]);
                }
            }
        }
    }
}

// ---------------------------------------------------------------------------
extern "C" void kernel_launch(void* const* d_in, const int* in_sizes, int n_in,
                              void* d_out, int out_size, void* d_ws, size_t ws_size,
                              hipStream_t stream) {
    const float* x = (const float*)d_in[0];        // [2,8,256,256] fp32
    const float* v = (const float*)d_in[1];        // [64,64] fp32
    float* outp = (float*)d_out;                   // [16,64,256,256] fp32
    unsigned short* frags = (unsigned short*)d_ws; // 4*2*64*8 bf16 = 8 KB

    build_A_frags<<<1, 256, 0, stream>>>(v, frags);

    dim3 grid(HSZ / TH, BC);                       // 32 x 16 = 512 blocks
    dim3 block(64, 4);                             // 256 threads = 4 waves
    ortho_mfma_kernel<<<grid, block, 0, stream>>>(x, frags, outp);
}

// Round 9
// 71.161 us; speedup vs baseline: 1.3023x; 1.1978x over previous
//
#include <hip/hip_runtime.h>

// Problem geometry
#define HSZ 256
#define WSZ 256
#define BC  16          // b*c
#define NCH 64          // 8x8 window channels
#define PADLO 3         // reflect pad (3,4)

// Tiling (R4 structure — best measured): block = 256 threads = 4 waves;
// wave w computes rows y0+2w, y0+2w+1, 64 cols.
#define TW 64
#define TH 8
#define NTHR 256        // actual block size — staging stride
#define TR 15           // TH + 7 halo rows
#define TC 71           // TW + 7 halo cols
#define TSTRIDE 80      // padded LDS row stride (floats)

typedef short bf16x8 __attribute__((ext_vector_type(8)));
typedef float f32x4  __attribute__((ext_vector_type(4)));

__device__ __forceinline__ int reflect_idx(int i) {
    i = (i < 0) ? -i : i;
    i = (i >= HSZ) ? (2 * (HSZ - 1) - i) : i;
    return i;
}

// fp32 -> bf16 RNE
__device__ __forceinline__ unsigned short f2bf(float f) {
    unsigned u = __builtin_bit_cast(unsigned, f);
    u += 0x7FFFu + ((u >> 16) & 1u);
    return (unsigned short)(u >> 16);
}

// ---------------------------------------------------------------------------
// Kernel 1 (v2 — short critical chain): A = prod_i (I - 2 v_i v_i^T/||v_i||^2).
// 256 threads; 4 lanes per A-row, lane owns 16 cols; dots via shfl_xor(16,32).
// Changes vs v1: v staged to LDS once; 2/||v_i||^2 precomputed in parallel;
// v_{i+1} and rs_{i+1} register-prefetched -> per-iter chain ~fma+shfl only.
// Wave w emits bf16 A-fragments for m-block mb=w:
//   frag(mb,c): lane l, elem j = A[k = c*32 + (l>>4)*8 + j][mb*16 + (l&15)]
// ws layout: ushort frags[4][2][64][8]  (8 KB)
// ---------------------------------------------------------------------------
__global__ void build_A_frags(const float* __restrict__ v,
                              unsigned short* __restrict__ frags) {
    __shared__ float vs[64][64];   // 16 KB: v rows
    __shared__ float rs[64];       // 2/||v_i||^2
    __shared__ float As[64][64];   // 16 KB: result

    const int t = threadIdx.x;        // 0..255
    const int w = t >> 6;             // wave 0..3
    const int l = t & 63;             // lane
    const int r = (w << 4) | (l & 15);// A-row owned (with 3 partner lanes)
    const int q = l >> 4;             // column quarter 0..3

    // Stage v into LDS (coalesced, one pass).
    for (int idx = t; idx < 64 * 64; idx += NTHR)
        ((float*)vs)[idx] = v[idx];
    __syncthreads();

    // Precompute rs[i] = 2/||v_i||^2 (threads 0..63, off critical path).
    if (t < 64) {
        const f32x4* vp = (const f32x4*)vs[t];
        float s0 = 0, s1 = 0, s2 = 0, s3 = 0;
#pragma unroll
        for (int c = 0; c < 4; ++c) {
            f32x4 vq = vp[c * 4 + 0];  // interleave 4 chains over 16 quads
            // simpler: accumulate quad c4 into chain c
            (void)vq;
        }
        // 4 independent chains over the 16 quads
        float ss[4] = {0, 0, 0, 0};
#pragma unroll
        for (int c = 0; c < 16; ++c) {
            f32x4 vq = vp[c];
            ss[c & 3] = fmaf(vq[0], vq[0], ss[c & 3]);
            ss[c & 3] = fmaf(vq[1], vq[1], ss[c & 3]);
            ss[c & 3] = fmaf(vq[2], vq[2], ss[c & 3]);
            ss[c & 3] = fmaf(vq[3], vq[3], ss[c & 3]);
        }
        rs[t] = 2.0f / ((ss[0] + ss[1]) + (ss[2] + ss[3]));
    }

    float row[16];
#pragma unroll
    for (int c = 0; c < 16; ++c) row[c] = (q * 16 + c == r) ? 1.0f : 0.0f;

    __syncthreads();

    // Prefetch iteration 0.
    const f32x4* vq0 = (const f32x4*)&vs[0][q * 16];
    f32x4 nv0 = vq0[0], nv1 = vq0[1], nv2 = vq0[2], nv3 = vq0[3];
    float nrs = rs[0];

    for (int i = 0; i < 64; ++i) {
        f32x4 c0 = nv0, c1 = nv1, c2 = nv2, c3 = nv3;
        const float rcur = nrs;
        if (i < 63) {                  // prefetch next iteration
            const f32x4* vqn = (const f32x4*)&vs[i + 1][q * 16];
            nv0 = vqn[0]; nv1 = vqn[1]; nv2 = vqn[2]; nv3 = vqn[3];
            nrs = rs[i + 1];
        }
        float vv[16];
#pragma unroll
        for (int j = 0; j < 4; ++j) { vv[j] = c0[j]; vv[4+j] = c1[j]; vv[8+j] = c2[j]; vv[12+j] = c3[j]; }

        float a0 = 0, a1 = 0, a2 = 0, a3 = 0;
#pragma unroll
        for (int c = 0; c < 4; ++c) {
            a0 = fmaf(row[c],      vv[c],      a0);
            a1 = fmaf(row[4 + c],  vv[4 + c],  a1);
            a2 = fmaf(row[8 + c],  vv[8 + c],  a2);
            a3 = fmaf(row[12 + c], vv[12 + c], a3);
        }
        float av = (a0 + a1) + (a2 + a3);
        av += __shfl_xor(av, 16);
        av += __shfl_xor(av, 32);

        const float scale = av * rcur;
#pragma unroll
        for (int c = 0; c < 16; ++c) row[c] = fmaf(-scale, vv[c], row[c]);
    }
#pragma unroll
    for (int c = 0; c < 16; ++c) As[r][q * 16 + c] = row[c];
    __syncthreads();

    const int ln = l & 15, lh = l >> 4;
    const int mb = w;
#pragma unroll
    for (int c2 = 0; c2 < 2; ++c2)
#pragma unroll
        for (int j = 0; j < 8; ++j) {
            float val = As[c2 * 32 + lh * 8 + j][mb * 16 + ln];
            frags[(((mb * 2 + c2) * 64) + l) * 8 + j] = f2bf(val);
        }
}

// ---------------------------------------------------------------------------
// Kernel 2 (R4 verbatim — best measured): per wave, 2 output rows x 64 cols
// x 64 ch via mfma_f32_16x16x32_bf16; nontemporal float4 stores.
// ---------------------------------------------------------------------------
__global__ __launch_bounds__(256)
void ortho_mfma_kernel(const float* __restrict__ x,
                       const unsigned short* __restrict__ frags,
                       float* __restrict__ out) {
    __shared__ float tile[TR][TSTRIDE];

    const int b  = blockIdx.z;
    const int y0 = blockIdx.y * TH;
    const int x0 = blockIdx.x * TW;
    const float* __restrict__ xb = x + (size_t)b * (HSZ * WSZ);

    const int tx = threadIdx.x;   // lane 0..63
    const int ty = threadIdx.y;   // wave 0..3
    const int tid = ty * TW + tx;

    // Stage halo tile with reflect padding. Stride = actual block size (256).
    for (int idx = tid; idx < TR * TC; idx += NTHR) {
        const int r  = idx / TC;
        const int c  = idx - r * TC;
        tile[r][c] = xb[reflect_idx(y0 + r - PADLO) * WSZ + reflect_idx(x0 + c - PADLO)];
    }

    const int ln = tx & 15, lh = tx >> 4;

    // Hoist A fragments (8 x 16B, L2-hot, reused for both rows)
    bf16x8 af[4][2];
#pragma unroll
    for (int mb = 0; mb < 4; ++mb)
#pragma unroll
        for (int c = 0; c < 2; ++c)
            af[mb][c] = *(const bf16x8*)(frags + ((mb * 2 + c) * 64 + tx) * 8);

    __syncthreads();

#pragma unroll
    for (int ry = 0; ry < 2; ++ry) {
        const int tyr = ty * 2 + ry;           // tile-row of this output row
        const int y   = y0 + tyr;

        // 16 consecutive fp32 per k-chunk -> bf16 once
        unsigned short bfv[2][16];
#pragma unroll
        for (int c = 0; c < 2; ++c) {
            const f32x4* rp = (const f32x4*)&tile[tyr + 4 * c + lh][4 * ln];
            f32x4 q0 = rp[0], q1 = rp[1], q2 = rp[2], q3 = rp[3];
            float fl[16];
#pragma unroll
            for (int j = 0; j < 4; ++j) { fl[j] = q0[j]; fl[4+j] = q1[j]; fl[8+j] = q2[j]; fl[12+j] = q3[j]; }
#pragma unroll
            for (int j = 0; j < 16; ++j) bfv[c][j] = f2bf(fl[j]);
        }

        // B fragments: chunk c, pixel-group g -> elems [g .. g+7]
        bf16x8 bfrag[2][4];
#pragma unroll
        for (int c = 0; c < 2; ++c)
#pragma unroll
            for (int g = 0; g < 4; ++g)
#pragma unroll
                for (int j = 0; j < 8; ++j)
                    bfrag[c][g][j] = (short)bfv[c][g + j];

        float* __restrict__ outb =
            out + (size_t)b * NCH * (HSZ * WSZ) + (size_t)y * WSZ + x0 + 4 * ln;

#pragma unroll
        for (int mb = 0; mb < 4; ++mb) {
            f32x4 acc[4];
#pragma unroll
            for (int g = 0; g < 4; ++g) {
                acc[g] = (f32x4){0.0f, 0.0f, 0.0f, 0.0f};
                acc[g] = __builtin_amdgcn_mfma_f32_16x16x32_bf16(af[mb][0], bfrag[0][g], acc[g], 0, 0, 0);
                acc[g] = __builtin_amdgcn_mfma_f32_16x16x32_bf16(af[mb][1], bfrag[1][g], acc[g], 0, 0, 0);
            }
#pragma unroll
            for (int r = 0; r < 4; ++r) {
                const int ch = mb * 16 + lh * 4 + r;
                f32x4 vv = { acc[0][r], acc[1][r], acc[2][r], acc[3][r] };
                __builtin_nontemporal_store(vv, (f32x4*)&outb[(size_t)ch * (HSZ * WSZ)]);
            }
        }
    }
}

// ---------------------------------------------------------------------------
extern "C" void kernel_launch(void* const* d_in, const int* in_sizes, int n_in,
                              void* d_out, int out_size, void* d_ws, size_t ws_size,
                              hipStream_t stream) {
    const float* x = (const float*)d_in[0];        // [2,8,256,256] fp32
    const float* v = (const float*)d_in[1];        // [64,64] fp32
    float* outp = (float*)d_out;                   // [16,64,256,256] fp32
    unsigned short* frags = (unsigned short*)d_ws; // 4*2*64*8 bf16 = 8 KB

    build_A_frags<<<1, 256, 0, stream>>>(v, frags);

    dim3 grid(WSZ / TW, HSZ / TH, BC);             // 4 x 32 x 16 = 2048 blocks
    dim3 block(TW, TH / 2);                        // 256 threads = 4 waves
    ortho_mfma_kernel<<<grid, block, 0, stream>>>(x, frags, outp);
}

// Round 10
// 68.406 us; speedup vs baseline: 1.3548x; 1.0403x over previous
//
#include <hip/hip_runtime.h>

// Problem geometry
#define HSZ 256
#define WSZ 256
#define BC  16          // b*c
#define NCH 64          // 8x8 window channels
#define HW  (HSZ * WSZ)
#define PADLO 3         // reflect pad (3,4)

// Plane-major tiling: block = (image b, channel-block mb, 16-row stripe ys).
// 256 threads = 4 waves; wave w computes rows y0+4w .. y0+4w+3, full 256 px,
// for 16 channels. Per channel the block writes 16 KB contiguous.
#define SR 16           // stripe rows per block
#define NTHR 256
#define TR (SR + 7)     // 23 halo rows
#define TC (WSZ + 7)    // 263 halo cols
#define TSTRIDE 272     // padded LDS row stride (floats): 252+15 < 272, 16B-aligned

typedef short bf16x8 __attribute__((ext_vector_type(8)));
typedef float f32x4  __attribute__((ext_vector_type(4)));

__device__ __forceinline__ int reflect_idx(int i) {
    i = (i < 0) ? -i : i;
    i = (i >= HSZ) ? (2 * (HSZ - 1) - i) : i;
    return i;
}

// fp32 -> bf16 RNE
__device__ __forceinline__ unsigned short f2bf(float f) {
    unsigned u = __builtin_bit_cast(unsigned, f);
    u += 0x7FFFu + ((u >> 16) & 1u);
    return (unsigned short)(u >> 16);
}

// ---------------------------------------------------------------------------
// Kernel 1 (R9-validated fast build): A = prod_i (I - 2 v_i v_i^T/||v_i||^2).
// v staged in LDS; 2/||v_i||^2 precomputed; next-iter register prefetch.
// Wave w emits bf16 A-fragments for m-block mb=w:
//   frag(mb,c): lane l, elem j = A[k = c*32 + (l>>4)*8 + j][mb*16 + (l&15)]
// ws layout: ushort frags[4][2][64][8]  (8 KB)
// ---------------------------------------------------------------------------
__global__ void build_A_frags(const float* __restrict__ v,
                              unsigned short* __restrict__ frags) {
    __shared__ float vs[64][64];
    __shared__ float rs[64];
    __shared__ float As[64][64];

    const int t = threadIdx.x;
    const int w = t >> 6;
    const int l = t & 63;
    const int r = (w << 4) | (l & 15);
    const int q = l >> 4;

    for (int idx = t; idx < 64 * 64; idx += NTHR)
        ((float*)vs)[idx] = v[idx];
    __syncthreads();

    if (t < 64) {
        const f32x4* vp = (const f32x4*)vs[t];
        float ss[4] = {0, 0, 0, 0};
#pragma unroll
        for (int c = 0; c < 16; ++c) {
            f32x4 vq = vp[c];
            ss[c & 3] = fmaf(vq[0], vq[0], ss[c & 3]);
            ss[c & 3] = fmaf(vq[1], vq[1], ss[c & 3]);
            ss[c & 3] = fmaf(vq[2], vq[2], ss[c & 3]);
            ss[c & 3] = fmaf(vq[3], vq[3], ss[c & 3]);
        }
        rs[t] = 2.0f / ((ss[0] + ss[1]) + (ss[2] + ss[3]));
    }

    float row[16];
#pragma unroll
    for (int c = 0; c < 16; ++c) row[c] = (q * 16 + c == r) ? 1.0f : 0.0f;

    __syncthreads();

    const f32x4* vq0 = (const f32x4*)&vs[0][q * 16];
    f32x4 nv0 = vq0[0], nv1 = vq0[1], nv2 = vq0[2], nv3 = vq0[3];
    float nrs = rs[0];

    for (int i = 0; i < 64; ++i) {
        f32x4 c0 = nv0, c1 = nv1, c2 = nv2, c3 = nv3;
        const float rcur = nrs;
        if (i < 63) {
            const f32x4* vqn = (const f32x4*)&vs[i + 1][q * 16];
            nv0 = vqn[0]; nv1 = vqn[1]; nv2 = vqn[2]; nv3 = vqn[3];
            nrs = rs[i + 1];
        }
        float vv[16];
#pragma unroll
        for (int j = 0; j < 4; ++j) { vv[j] = c0[j]; vv[4+j] = c1[j]; vv[8+j] = c2[j]; vv[12+j] = c3[j]; }

        float a0 = 0, a1 = 0, a2 = 0, a3 = 0;
#pragma unroll
        for (int c = 0; c < 4; ++c) {
            a0 = fmaf(row[c],      vv[c],      a0);
            a1 = fmaf(row[4 + c],  vv[4 + c],  a1);
            a2 = fmaf(row[8 + c],  vv[8 + c],  a2);
            a3 = fmaf(row[12 + c], vv[12 + c], a3);
        }
        float av = (a0 + a1) + (a2 + a3);
        av += __shfl_xor(av, 16);
        av += __shfl_xor(av, 32);

        const float scale = av * rcur;
#pragma unroll
        for (int c = 0; c < 16; ++c) row[c] = fmaf(-scale, vv[c], row[c]);
    }
#pragma unroll
    for (int c = 0; c < 16; ++c) As[r][q * 16 + c] = row[c];
    __syncthreads();

    const int ln = l & 15, lh = l >> 4;
    const int mb = w;
#pragma unroll
    for (int c2 = 0; c2 < 2; ++c2)
#pragma unroll
        for (int j = 0; j < 8; ++j) {
            float val = As[c2 * 32 + lh * 8 + j][mb * 16 + ln];
            frags[(((mb * 2 + c2) * 64) + l) * 8 + j] = f2bf(val);
        }
}

// ---------------------------------------------------------------------------
// Kernel 2: plane-major. Block (b, mb, ys): 16 channels x 16 rows x 256 px.
// Wave w: rows y0+4w..y0+4w+3 over x-quarters qq. Inner fragment math is the
// R4-verified mapping. Plain cached stores; per channel the block's writes
// are 16 KB contiguous; XCD-swizzled so each XCD owns whole-image slabs.
// ---------------------------------------------------------------------------
__global__ __launch_bounds__(256)
void ortho_mfma_plane(const float* __restrict__ x,
                      const unsigned short* __restrict__ frags,
                      float* __restrict__ out) {
    __shared__ float tile[TR][TSTRIDE];   // 23 x 272 x 4B = 25 KB

    // XCD-bijective swizzle: 1024 blocks, 8 XCDs (dispatch ~round-robin).
    // XCD k gets logical ids [k*128,(k+1)*128) = 2 whole images (contiguous 32 MB out).
    const int bid = blockIdx.x;
    const int lid = (bid & 7) * 128 + (bid >> 3);
    const int b   = lid >> 6;          // /64: image
    const int rem = lid & 63;
    const int mb  = rem >> 4;          // channel-block 0..3
    const int ys  = rem & 15;          // row stripe 0..15
    const int y0  = ys * SR;

    const float* __restrict__ xb = x + (size_t)b * HW;

    const int tx = threadIdx.x;   // lane 0..63
    const int wv = threadIdx.y;   // wave 0..3
    const int tid = wv * 64 + tx;

    // Stage halo stripe (23 x 263) with reflect padding; linear, coalesced.
    for (int idx = tid; idx < TR * TC; idx += NTHR) {
        const int r = idx / TC;
        const int c = idx - r * TC;
        tile[r][c] = xb[(size_t)reflect_idx(y0 + r - PADLO) * WSZ + reflect_idx(c - PADLO)];
    }

    const int ln = tx & 15, lh = tx >> 4;

    // A fragments for this block's single mb (2 x 16B)
    const bf16x8 af0 = *(const bf16x8*)(frags + ((mb * 2 + 0) * 64 + tx) * 8);
    const bf16x8 af1 = *(const bf16x8*)(frags + ((mb * 2 + 1) * 64 + tx) * 8);

    __syncthreads();

    float* __restrict__ outp = out + (size_t)(b * NCH + mb * 16) * HW;

#pragma unroll
    for (int rr = 0; rr < 4; ++rr) {
        const int tyr = wv * 4 + rr;          // tile-relative output row
        const int y   = y0 + tyr;

#pragma unroll
        for (int qq = 0; qq < 4; ++qq) {
            // 16 consecutive fp32 per k-chunk -> bf16 (R4-verbatim path)
            unsigned short bfv[2][16];
#pragma unroll
            for (int c = 0; c < 2; ++c) {
                const f32x4* rp = (const f32x4*)&tile[tyr + 4 * c + lh][64 * qq + 4 * ln];
                f32x4 q0 = rp[0], q1 = rp[1], q2 = rp[2], q3 = rp[3];
                float fl[16];
#pragma unroll
                for (int j = 0; j < 4; ++j) { fl[j] = q0[j]; fl[4+j] = q1[j]; fl[8+j] = q2[j]; fl[12+j] = q3[j]; }
#pragma unroll
                for (int j = 0; j < 16; ++j) bfv[c][j] = f2bf(fl[j]);
            }

            // B fragments: chunk c, pixel-group g -> elems [g .. g+7]
            bf16x8 bfrag[2][4];
#pragma unroll
            for (int c = 0; c < 2; ++c)
#pragma unroll
                for (int g = 0; g < 4; ++g)
#pragma unroll
                    for (int j = 0; j < 8; ++j)
                        bfrag[c][g][j] = (short)bfv[c][g + j];

            f32x4 acc[4];
#pragma unroll
            for (int g = 0; g < 4; ++g) {
                acc[g] = (f32x4){0.0f, 0.0f, 0.0f, 0.0f};
                acc[g] = __builtin_amdgcn_mfma_f32_16x16x32_bf16(af0, bfrag[0][g], acc[g], 0, 0, 0);
                acc[g] = __builtin_amdgcn_mfma_f32_16x16x32_bf16(af1, bfrag[1][g], acc[g], 0, 0, 0);
            }

            // Store: ch-local = lh*4 + r; px = 64*qq + 4*ln + g. Plain stores
            // (L2 write-back); block's per-channel footprint = 16 KB contiguous.
#pragma unroll
            for (int r = 0; r < 4; ++r) {
                const int chl = lh * 4 + r;
                f32x4 vv = { acc[0][r], acc[1][r], acc[2][r], acc[3][r] };
                *(f32x4*)&outp[(size_t)chl * HW + (size_t)y * WSZ + 64 * qq + 4 * ln] = vv;
            }
        }
    }
}

// ---------------------------------------------------------------------------
extern "C" void kernel_launch(void* const* d_in, const int* in_sizes, int n_in,
                              void* d_out, int out_size, void* d_ws, size_t ws_size,
                              hipStream_t stream) {
    const float* x = (const float*)d_in[0];        // [2,8,256,256] fp32
    const float* v = (const float*)d_in[1];        // [64,64] fp32
    float* outp = (float*)d_out;                   // [16,64,256,256] fp32
    unsigned short* frags = (unsigned short*)d_ws; // 4*2*64*8 bf16 = 8 KB

    build_A_frags<<<1, 256, 0, stream>>>(v, frags);

    dim3 grid(BC * 4 * 16);                        // 1024 blocks (b, mb, ys)
    dim3 block(64, 4);                             // 256 threads = 4 waves
    ortho_mfma_plane<<<grid, block, 0, stream>>>(x, frags, outp);
}